// Round 8
// baseline (173.949 us; speedup 1.0000x reference)
//
#include <hip/hip_runtime.h>

#define BINS 4096            // 64 * 64
#define HIST_BLOCKS 2048
#define HIST_THREADS 256     // 4 waves/block; each wave gets a PRIVATE histogram
#define PAIRS 8              // 8 (p,c) int4 pairs per thread = 16 dwordx4 in flight
#define NWAVE (HIST_THREADS / 64)

typedef int intx4 __attribute__((ext_vector_type(4)));

// out[i] = transitions_in[i] for i < bins; out[bins] = total_in + n_events
__global__ void topo_init_kernel(const float* __restrict__ transitions,
                                 const float* __restrict__ total,
                                 float* __restrict__ out,
                                 float n_events_f, int bins) {
    int i = blockIdx.x * blockDim.x + threadIdx.x;
    if (i < bins) out[i] = transitions[i];
    if (i == 0) out[bins] = total[0] + n_events_f;
}

#define CONS(Pk, Ck)                                    \
    atomicAdd(&hw[(Pk.x << 6) | Ck.x], 1u);             \
    atomicAdd(&hw[(Pk.y << 6) | Ck.y], 1u);             \
    atomicAdd(&hw[(Pk.z << 6) | Ck.z], 1u);             \
    atomicAdd(&hw[(Pk.w << 6) | Ck.w], 1u)

#define WAITPAIR(N, Pk, Ck)                             \
    asm volatile("s_waitcnt vmcnt(" #N ")"              \
                 : "+v"(Pk), "+v"(Ck)::"memory")

// 16 global_load_dwordx4 issued in one asm block; "=&v" early-clobber is
// REQUIRED (R4 crash: outputs aliased onto still-live address inputs).
#define LOAD16_ASM(P0,C0,P1,C1,P2,C2,P3,C3,P4,C4,P5,C5,P6,C6,P7,C7,          \
                   o0,o1,o2,o3,o4,o5,o6,o7,pb,cb)                            \
    asm volatile(                                                            \
        "global_load_dwordx4 %[rP0], %[ro0], %[rpb]\n\t"                     \
        "global_load_dwordx4 %[rC0], %[ro0], %[rcb]\n\t"                     \
        "global_load_dwordx4 %[rP1], %[ro1], %[rpb]\n\t"                     \
        "global_load_dwordx4 %[rC1], %[ro1], %[rcb]\n\t"                     \
        "global_load_dwordx4 %[rP2], %[ro2], %[rpb]\n\t"                     \
        "global_load_dwordx4 %[rC2], %[ro2], %[rcb]\n\t"                     \
        "global_load_dwordx4 %[rP3], %[ro3], %[rpb]\n\t"                     \
        "global_load_dwordx4 %[rC3], %[ro3], %[rcb]\n\t"                     \
        "global_load_dwordx4 %[rP4], %[ro4], %[rpb]\n\t"                     \
        "global_load_dwordx4 %[rC4], %[ro4], %[rcb]\n\t"                     \
        "global_load_dwordx4 %[rP5], %[ro5], %[rpb]\n\t"                     \
        "global_load_dwordx4 %[rC5], %[ro5], %[rcb]\n\t"                     \
        "global_load_dwordx4 %[rP6], %[ro6], %[rpb]\n\t"                     \
        "global_load_dwordx4 %[rC6], %[ro6], %[rcb]\n\t"                     \
        "global_load_dwordx4 %[rP7], %[ro7], %[rpb]\n\t"                     \
        "global_load_dwordx4 %[rC7], %[ro7], %[rcb]"                         \
        : [rP0] "=&v"(P0), [rC0] "=&v"(C0), [rP1] "=&v"(P1), [rC1] "=&v"(C1),\
          [rP2] "=&v"(P2), [rC2] "=&v"(C2), [rP3] "=&v"(P3), [rC3] "=&v"(C3),\
          [rP4] "=&v"(P4), [rC4] "=&v"(C4), [rP5] "=&v"(P5), [rC5] "=&v"(C5),\
          [rP6] "=&v"(P6), [rC6] "=&v"(C6), [rP7] "=&v"(P7), [rC7] "=&v"(C7) \
        : [ro0] "v"(o0), [ro1] "v"(o1), [ro2] "v"(o2), [ro3] "v"(o3),        \
          [ro4] "v"(o4), [ro5] "v"(o5), [ro6] "v"(o6), [ro7] "v"(o7),        \
          [rpb] "s"(pb), [rcb] "s"(cb)                                       \
        : "memory")

__global__ void __launch_bounds__(HIST_THREADS)
topo_hist_kernel(const int* __restrict__ prev,
                 const int* __restrict__ curr,
                 float* __restrict__ out, int n) {
    // R8: PER-WAVE PRIVATE histograms. R7 proved the stall is not VMEM/DS
    // coexistence (full phase separation = null). The remaining untouched
    // structural variable across ALL rounds: 8 waves hammering ONE shared
    // h[4096] with LDS atomics. Inter-wave same-address/arbitration
    // serialization at the LDS atomic unit is NOT counted by
    // SQ_LDS_BANK_CONFLICT (which only sees intra-wave-instr collisions).
    // 4 waves/block x private 16 KB hist = 64 KB/block, 2 blocks/CU.
    __shared__ unsigned int h[NWAVE * BINS];
    {   // vectorized zero-init: 16 uint4-stores per thread
        uint4* hz = (uint4*)h;
        const uint4 z = {0u, 0u, 0u, 0u};
        for (int i = threadIdx.x; i < (NWAVE * BINS) >> 2; i += HIST_THREADS)
            hz[i] = z;
    }
    __syncthreads();
    unsigned int* hw = &h[(threadIdx.x >> 6) << 12];   // this wave's histogram

    const int n4 = n >> 2;
    const int total_threads = gridDim.x * HIST_THREADS;
    const int tid = blockIdx.x * HIST_THREADS + threadIdx.x;

    if (n4 == total_threads * PAIRS && (n & 3) == 0) {
        // Proven-best load schedule (R5): 16-deep asm cascade, counted vmcnt.
        const int base = blockIdx.x * (HIST_THREADS * PAIRS) + threadIdx.x;
        const unsigned st = HIST_THREADS * 16u;          // 4 KB between k's
        const unsigned o0 = (unsigned)base * 16u;
        const unsigned o1 = o0 + st,     o2 = o0 + 2 * st, o3 = o0 + 3 * st,
                       o4 = o0 + 4 * st, o5 = o0 + 5 * st, o6 = o0 + 6 * st,
                       o7 = o0 + 7 * st;

        intx4 P0, P1, P2, P3, P4, P5, P6, P7;
        intx4 C0, C1, C2, C3, C4, C5, C6, C7;
        LOAD16_ASM(P0,C0,P1,C1,P2,C2,P3,C3,P4,C4,P5,C5,P6,C6,P7,C7,
                   o0,o1,o2,o3,o4,o5,o6,o7,prev,curr);

        WAITPAIR(14, P0, C0); CONS(P0, C0);
        WAITPAIR(12, P1, C1); CONS(P1, C1);
        WAITPAIR(10, P2, C2); CONS(P2, C2);
        WAITPAIR(8,  P3, C3); CONS(P3, C3);
        WAITPAIR(6,  P4, C4); CONS(P4, C4);
        WAITPAIR(4,  P5, C5); CONS(P5, C5);
        WAITPAIR(2,  P6, C6); CONS(P6, C6);
        WAITPAIR(0,  P7, C7); CONS(P7, C7);
    } else {
        // Generic fallback: grid-stride (correct for any n), wave-private hist.
        const int4* __restrict__ p4 = (const int4*)prev;
        const int4* __restrict__ c4 = (const int4*)curr;
        for (int i = tid; i < n4; i += total_threads) {
            int4 p = p4[i];
            int4 c = c4[i];
            atomicAdd(&hw[(p.x << 6) | c.x], 1u);
            atomicAdd(&hw[(p.y << 6) | c.y], 1u);
            atomicAdd(&hw[(p.z << 6) | c.z], 1u);
            atomicAdd(&hw[(p.w << 6) | c.w], 1u);
        }
        for (int t = (n4 << 2) + tid; t < n; t += total_threads) {
            atomicAdd(&hw[(prev[t] << 6) | curr[t]], 1u);
        }
    }

    __syncthreads();
    // Flush: sum the NWAVE private hists per bin, one global atomic per bin.
    // (R1: global float-atomic flush at this scale is free.)
    for (int b = threadIdx.x; b < BINS; b += HIST_THREADS) {
        unsigned int c = h[b] + h[b + BINS] + h[b + 2 * BINS] + h[b + 3 * BINS];
        if (c) atomicAdd(&out[b], (float)c);
    }
}

extern "C" void kernel_launch(void* const* d_in, const int* in_sizes, int n_in,
                              void* d_out, int out_size, void* d_ws, size_t ws_size,
                              hipStream_t stream) {
    const int*   prev        = (const int*)d_in[0];
    const int*   curr        = (const int*)d_in[1];
    const float* transitions = (const float*)d_in[2];
    const float* total       = (const float*)d_in[3];
    float* out = (float*)d_out;

    const int n    = in_sizes[0];
    const int bins = in_sizes[2];   // 4096

    // 1) initialize output: copy transitions input, set total = total_in + n
    int init_blocks = (bins + 1 + 255) / 256;
    topo_init_kernel<<<init_blocks, 256, 0, stream>>>(transitions, total, out,
                                                      (float)n, bins);

    // 2) histogram: wave-private LDS hists + R5 load cascade
    topo_hist_kernel<<<HIST_BLOCKS, HIST_THREADS, 0, stream>>>(prev, curr, out, n);
}